// Round 1
// baseline (3841.862 us; speedup 1.0000x reference)
//
#include <hip/hip_runtime.h>
#include <hip/hip_bf16.h>

#define Bn 64
#define Ln 2048
#define Hn 128
#define Vn 32000
#define THn 256            // 2*H
#define LAMBDA_ (1.0f/2048.0f)

// ---------------------------------------------------------------------------
// Phase 1: embed gather + FF1 + FF2 + residual + LayerNorm + k-projection,
// writing kn (normalized k) and ||k|| per token. 64 tokens per workgroup.
// Weights are read via wave-uniform scalar loads (o/i indices forced uniform
// with readfirstlane) -> s_load chains, zero LDS traffic in inner loops.
// ---------------------------------------------------------------------------
__global__ __launch_bounds__(256) void p1_fused(
    const int* __restrict__ seq,
    const float* __restrict__ embed_w,
    const float* __restrict__ ff_w1, const float* __restrict__ ff_b1,
    const float* __restrict__ ff_w2, const float* __restrict__ ff_b2,
    const float* __restrict__ ln_g, const float* __restrict__ ln_b,
    const float* __restrict__ kp_w,
    float* __restrict__ kn_all, float* __restrict__ norm_all)
{
  __shared__ __align__(16) float u_lds[16384];  // [256][64] u; later k_stage [64][132]
  __shared__ __align__(16) float h_lds[8192];   // [128][64] h; later hn
  __shared__ float part1[256], part2[256], rinv_lds[64];
  __shared__ int sid_lds[64];

  const int tid  = threadIdx.x;
  const int lane = tid & 63;                      // token within tile
  const int w    = __builtin_amdgcn_readfirstlane(tid >> 6);  // wave id (uniform)
  const int tile0 = blockIdx.x * 64;              // first global token of tile

  if (tid < 64) sid_lds[tid] = seq[tile0 + tid];
  __syncthreads();                                // B1

  // gather embed rows -> h_lds[j][t]
  {
    const int t = tid >> 2;
    const int part = tid & 3;
    const float4* erow =
        reinterpret_cast<const float4*>(embed_w + (size_t)sid_lds[t] * Hn) + part * 8;
    #pragma unroll
    for (int c = 0; c < 8; ++c) {
      float4 v = erow[c];
      int j = part * 32 + c * 4;
      h_lds[(j+0)*64 + t] = v.x;
      h_lds[(j+1)*64 + t] = v.y;
      h_lds[(j+2)*64 + t] = v.z;
      h_lds[(j+3)*64 + t] = v.w;
    }
  }
  __syncthreads();                                // B2

  // own token's h row into registers (conflict-free column reads)
  float hreg[Hn];
  #pragma unroll
  for (int j = 0; j < Hn; ++j) hreg[j] = h_lds[j*64 + lane];

  // FF1: wave w computes u[o][t] for o in [w*64, w*64+64)
  #pragma unroll 1
  for (int oi = 0; oi < 64; ++oi) {
    const int o = w * 64 + oi;                    // uniform
    const float* w1r = ff_w1 + o * Hn;            // scalar loads
    float acc = 0.f;
    #pragma unroll
    for (int j = 0; j < Hn; ++j) acc += hreg[j] * w1r[j];
    acc += ff_b1[o];
    u_lds[o*64 + lane] = fmaxf(acc, 0.f);
  }
  __syncthreads();                                // B3

  // FF2 + bias + residual: wave w computes x[i] for i in [w*32, w*32+32)
  const int i0 = w * 32;
  float x[32];
  #pragma unroll
  for (int ii = 0; ii < 32; ++ii) x[ii] = 0.f;
  #pragma unroll 1
  for (int ob = 0; ob < 32; ++ob) {
    float uv[8];
    #pragma unroll
    for (int oo = 0; oo < 8; ++oo) uv[oo] = u_lds[(ob*8+oo)*64 + lane];
    #pragma unroll
    for (int ii = 0; ii < 32; ++ii) {
      const float* w2r = ff_w2 + (i0+ii)*THn + ob*8;   // 8 contiguous scalars
      #pragma unroll
      for (int oo = 0; oo < 8; ++oo) x[ii] += uv[oo] * w2r[oo];
    }
  }
  float s1 = 0.f, s2 = 0.f;
  #pragma unroll
  for (int ii = 0; ii < 32; ++ii) {
    x[ii] += ff_b2[i0+ii] + h_lds[(i0+ii)*64 + lane];  // residual
    s1 += x[ii];
    s2 += x[ii]*x[ii];
  }
  part1[w*64+lane] = s1;
  part2[w*64+lane] = s2;
  __syncthreads();                                // B4

  float mu = 0.f, ms = 0.f;
  #pragma unroll
  for (int ww = 0; ww < 4; ++ww) { mu += part1[ww*64+lane]; ms += part2[ww*64+lane]; }
  mu *= (1.0f/128.0f); ms *= (1.0f/128.0f);
  const float rstd = rsqrtf(ms - mu*mu + 1e-5f);
  #pragma unroll
  for (int ii = 0; ii < 32; ++ii) {
    float hn = (x[ii]-mu)*rstd*ln_g[i0+ii] + ln_b[i0+ii];
    h_lds[(i0+ii)*64 + lane] = hn;                // overwrite own rows (disjoint)
  }
  __syncthreads();                                // B5

  // k projection: wave w computes k[o] for o in [w*32, w*32+32)
  float kacc[32];
  #pragma unroll
  for (int oo = 0; oo < 32; ++oo) kacc[oo] = 0.f;
  const int o0 = w * 32;
  #pragma unroll 1
  for (int ib = 0; ib < 16; ++ib) {
    float hv[8];
    #pragma unroll
    for (int jj = 0; jj < 8; ++jj) hv[jj] = h_lds[(ib*8+jj)*64 + lane];
    #pragma unroll
    for (int oo = 0; oo < 32; ++oo) {
      const float* kpr = kp_w + (o0+oo)*Hn + ib*8;
      #pragma unroll
      for (int jj = 0; jj < 8; ++jj) kacc[oo] += hv[jj] * kpr[jj];
    }
  }
  float* k_stage = u_lds;                         // [64][132], u is dead
  float ps = 0.f;
  #pragma unroll
  for (int oo = 0; oo < 32; ++oo) {
    k_stage[lane*132 + o0 + oo] = kacc[oo];
    ps += kacc[oo]*kacc[oo];
  }
  part1[w*64+lane] = ps;
  __syncthreads();                                // B6
  if (tid < 64) {
    float nn = part1[tid] + part1[64+tid] + part1[128+tid] + part1[192+tid];
    float nrm = sqrtf(nn);
    norm_all[tile0 + tid] = nrm;
    rinv_lds[tid] = 1.0f / fmaxf(nrm, 1e-12f);
  }
  __syncthreads();                                // B7
  // coalesced write of kn = k * (1/max(||k||,eps))
  #pragma unroll
  for (int c = 0; c < 32; ++c) {
    int gi = c*256 + tid;
    int t = gi >> 7, o = gi & 127;
    kn_all[(size_t)tile0*Hn + gi] = k_stage[t*132 + o] * rinv_lds[t];
  }
}

// ---------------------------------------------------------------------------
// Phase 2: sequential gated delta-rule scan. One workgroup per batch.
// M (128x128 fp32) lives in VGPRs: thread = (row = tid>>1, col-half = tid&1),
// 64 elements each. 2 barriers per step.
// ---------------------------------------------------------------------------
__global__ __launch_bounds__(256) void p2_scan(
    const float* __restrict__ kn_all, const float* __restrict__ norm_all,
    float* __restrict__ read_ws)
{
  const int tid  = threadIdx.x;
  const int lane = tid & 63;
  const int w    = tid >> 6;
  const int r    = tid >> 1;          // row 0..127
  const int ch   = tid & 1;           // column half
  const int b    = blockIdx.x;
  __shared__ __align__(16) float kn_lds[128];
  __shared__ float red[4];
  __shared__ float norm_sh;

  float M[64];
  #pragma unroll
  for (int c = 0; c < 64; ++c) M[c] = 0.f;

  const float* knb = kn_all + (size_t)b * Ln * Hn;
  const float* nb  = norm_all + (size_t)b * Ln;

  #pragma unroll 1
  for (int l = 0; l < Ln; ++l) {
    if (tid < 128) kn_lds[tid] = knb[(size_t)l*Hn + tid];
    if (tid == 128) norm_sh = nb[l];
    __syncthreads();                  // B_a
    const float nrm = norm_sh;

    float kn[64];
    const float4* kv = reinterpret_cast<const float4*>(kn_lds + ch*64);
    #pragma unroll
    for (int c4 = 0; c4 < 16; ++c4) {
      float4 v = kv[c4];
      kn[c4*4+0] = v.x; kn[c4*4+1] = v.y; kn[c4*4+2] = v.z; kn[c4*4+3] = v.w;
    }
    float acc = 0.f;
    #pragma unroll
    for (int c = 0; c < 64; ++c) acc += M[c]*kn[c];
    const float vp = acc + __shfl_xor(acc, 1);   // full-row M.kn

    if (l == Ln-1) {                  // last position is the query
      if (ch == 0) read_ws[b*Hn + r] = nrm * vp; // read = M@q, q = nrm*kn
      break;
    }

    const float dr = nrm * kn_lds[r] - vp;       // d = k - vp
    float sq = (ch == 0) ? dr*dr : 0.f;
    #pragma unroll
    for (int off = 32; off >= 1; off >>= 1) sq += __shfl_xor(sq, off);
    if (lane == 0) red[w] = sq;
    __syncthreads();                  // B_b
    const float dn2 = red[0]+red[1]+red[2]+red[3];

    if (sqrtf(dn2) >= 0.4f * nrm) {   // fire gate (whole-workgroup uniform)
      const float c1 = LAMBDA_ * dr;
      #pragma unroll
      for (int c = 0; c < 64; ++c) M[c] += c1 * kn[c];
    }
    // no trailing barrier needed: next iter's LDS writes happen after B_b,
    // all reads of kn_lds/norm_sh happened before B_b.
  }
}

// ---------------------------------------------------------------------------
// Phase 3a: o1 = read @ rp_w^T + rp_b   (tiny)
// ---------------------------------------------------------------------------
__global__ __launch_bounds__(128) void p3a(
    const float* __restrict__ read_ws, const float* __restrict__ rp_w,
    const float* __restrict__ rp_b, float* __restrict__ o1_ws)
{
  __shared__ float rd[128];
  const int b = blockIdx.x, t = threadIdx.x;
  rd[t] = read_ws[b*Hn + t];
  __syncthreads();
  float acc = rp_b[t];
  const float* wr = rp_w + t*Hn;
  #pragma unroll 4
  for (int i = 0; i < Hn; ++i) acc += rd[i]*wr[i];
  o1_ws[b*Hn + t] = acc;
}

// ---------------------------------------------------------------------------
// Phase 3b: out = o1 @ out_w^T + out_b. Thread = one vocab column, all 64
// batches accumulated in registers; out_w streamed exactly once.
// ---------------------------------------------------------------------------
__global__ __launch_bounds__(256) void p3b(
    const float* __restrict__ o1_ws, const float* __restrict__ out_w,
    const float* __restrict__ out_b, float* __restrict__ out)
{
  __shared__ __align__(16) float o1[8192];       // [64][128]
  const int tid = threadIdx.x;
  #pragma unroll
  for (int c = 0; c < 32; ++c) o1[c*256+tid] = o1_ws[c*256+tid];
  __syncthreads();
  const int v = blockIdx.x*256 + tid;            // 125*256 == 32000 exactly
  float acc[64];
  const float ob = out_b[v];
  #pragma unroll
  for (int bb = 0; bb < 64; ++bb) acc[bb] = ob;
  const float4* wrow = reinterpret_cast<const float4*>(out_w + (size_t)v*Hn);
  #pragma unroll 1
  for (int r4 = 0; r4 < 32; ++r4) {
    const float4 wv = wrow[r4];
    #pragma unroll
    for (int bb = 0; bb < 64; ++bb) {
      const float4 ov = *reinterpret_cast<const float4*>(&o1[bb*Hn + r4*4]);
      acc[bb] += wv.x*ov.x + wv.y*ov.y + wv.z*ov.z + wv.w*ov.w;
    }
  }
  #pragma unroll
  for (int bb = 0; bb < 64; ++bb) out[(size_t)bb*Vn + v] = acc[bb];
}

// ---------------------------------------------------------------------------
extern "C" void kernel_launch(void* const* d_in, const int* in_sizes, int n_in,
                              void* d_out, int out_size, void* d_ws, size_t ws_size,
                              hipStream_t stream)
{
  const int*   seq     = (const int*)  d_in[0];
  const float* embed_w = (const float*)d_in[1];
  const float* ff_w1   = (const float*)d_in[2];
  const float* ff_b1   = (const float*)d_in[3];
  const float* ff_w2   = (const float*)d_in[4];
  const float* ff_b2   = (const float*)d_in[5];
  const float* ln_g    = (const float*)d_in[6];
  const float* ln_b    = (const float*)d_in[7];
  const float* kp_w    = (const float*)d_in[8];
  const float* rp_w    = (const float*)d_in[9];
  const float* rp_b    = (const float*)d_in[10];
  const float* out_w   = (const float*)d_in[11];
  const float* out_b   = (const float*)d_in[12];

  float* ws       = (float*)d_ws;
  float* kn_all   = ws;                               // B*L*H   = 16,777,216 f
  float* norm_all = ws + (size_t)Bn*Ln*Hn;            // B*L     = 131,072 f
  float* read_ws  = norm_all + (size_t)Bn*Ln;         // B*H     = 8,192 f
  float* o1_ws    = read_ws + Bn*Hn;                  // B*H     = 8,192 f
  // total ws use: ~67.7 MB

  p1_fused<<<dim3(2048), dim3(256), 0, stream>>>(
      seq, embed_w, ff_w1, ff_b1, ff_w2, ff_b2, ln_g, ln_b, kp_w, kn_all, norm_all);
  p2_scan<<<dim3(64), dim3(256), 0, stream>>>(kn_all, norm_all, read_ws);
  p3a<<<dim3(64), dim3(128), 0, stream>>>(read_ws, rp_w, rp_b, o1_ws);
  p3b<<<dim3(125), dim3(256), 0, stream>>>(o1_ws, out_w, out_b, (float*)d_out);
}

// Round 2
// 3043.187 us; speedup vs baseline: 1.2624x; 1.2624x over previous
//
#include <hip/hip_runtime.h>
#include <hip/hip_bf16.h>

#define Bn 64
#define Ln 2048
#define Hn 128
#define Vn 32000
#define THn 256            // 2*H
#define LAMBDA_ (1.0f/2048.0f)

// ---------------------------------------------------------------------------
// Phase 1: embed gather + FF1 + FF2 + residual + LayerNorm + k-projection,
// writing kn (normalized k) and ||k|| per token. 64 tokens per workgroup.
// ---------------------------------------------------------------------------
__global__ __launch_bounds__(256) void p1_fused(
    const int* __restrict__ seq,
    const float* __restrict__ embed_w,
    const float* __restrict__ ff_w1, const float* __restrict__ ff_b1,
    const float* __restrict__ ff_w2, const float* __restrict__ ff_b2,
    const float* __restrict__ ln_g, const float* __restrict__ ln_b,
    const float* __restrict__ kp_w,
    float* __restrict__ kn_all, float* __restrict__ norm_all)
{
  __shared__ __align__(16) float u_lds[16384];  // [256][64] u; later k_stage [64][132]
  __shared__ __align__(16) float h_lds[8192];   // [128][64] h; later hn
  __shared__ float part1[256], part2[256], rinv_lds[64];
  __shared__ int sid_lds[64];

  const int tid  = threadIdx.x;
  const int lane = tid & 63;                      // token within tile
  const int w    = __builtin_amdgcn_readfirstlane(tid >> 6);  // wave id (uniform)
  const int tile0 = blockIdx.x * 64;              // first global token of tile

  if (tid < 64) sid_lds[tid] = seq[tile0 + tid];
  __syncthreads();                                // B1

  // gather embed rows -> h_lds[j][t]
  {
    const int t = tid >> 2;
    const int part = tid & 3;
    const float4* erow =
        reinterpret_cast<const float4*>(embed_w + (size_t)sid_lds[t] * Hn) + part * 8;
    #pragma unroll
    for (int c = 0; c < 8; ++c) {
      float4 v = erow[c];
      int j = part * 32 + c * 4;
      h_lds[(j+0)*64 + t] = v.x;
      h_lds[(j+1)*64 + t] = v.y;
      h_lds[(j+2)*64 + t] = v.z;
      h_lds[(j+3)*64 + t] = v.w;
    }
  }
  __syncthreads();                                // B2

  // own token's h row into registers (conflict-free column reads)
  float hreg[Hn];
  #pragma unroll
  for (int j = 0; j < Hn; ++j) hreg[j] = h_lds[j*64 + lane];

  // FF1: wave w computes u[o][t] for o in [w*64, w*64+64)
  #pragma unroll 1
  for (int oi = 0; oi < 64; ++oi) {
    const int o = w * 64 + oi;                    // uniform
    const float* w1r = ff_w1 + o * Hn;            // scalar loads
    float a0 = 0.f, a1 = 0.f, a2 = 0.f, a3 = 0.f;
    #pragma unroll
    for (int j = 0; j < 32; ++j) {
      a0 += hreg[j]      * w1r[j];
      a1 += hreg[32+j]   * w1r[32+j];
      a2 += hreg[64+j]   * w1r[64+j];
      a3 += hreg[96+j]   * w1r[96+j];
    }
    float acc = (a0+a1)+(a2+a3) + ff_b1[o];
    u_lds[o*64 + lane] = fmaxf(acc, 0.f);
  }
  __syncthreads();                                // B3

  // FF2 + bias + residual: wave w computes x[i] for i in [w*32, w*32+32)
  const int i0 = w * 32;
  float x[32];
  #pragma unroll
  for (int ii = 0; ii < 32; ++ii) x[ii] = 0.f;
  #pragma unroll 1
  for (int ob = 0; ob < 32; ++ob) {
    float uv[8];
    #pragma unroll
    for (int oo = 0; oo < 8; ++oo) uv[oo] = u_lds[(ob*8+oo)*64 + lane];
    #pragma unroll
    for (int ii = 0; ii < 32; ++ii) {
      const float* w2r = ff_w2 + (i0+ii)*THn + ob*8;   // 8 contiguous scalars
      #pragma unroll
      for (int oo = 0; oo < 8; ++oo) x[ii] += uv[oo] * w2r[oo];
    }
  }
  float s1 = 0.f, s2 = 0.f;
  #pragma unroll
  for (int ii = 0; ii < 32; ++ii) {
    x[ii] += ff_b2[i0+ii] + h_lds[(i0+ii)*64 + lane];  // residual
    s1 += x[ii];
    s2 += x[ii]*x[ii];
  }
  part1[w*64+lane] = s1;
  part2[w*64+lane] = s2;
  __syncthreads();                                // B4

  float mu = 0.f, ms = 0.f;
  #pragma unroll
  for (int ww = 0; ww < 4; ++ww) { mu += part1[ww*64+lane]; ms += part2[ww*64+lane]; }
  mu *= (1.0f/128.0f); ms *= (1.0f/128.0f);
  const float rstd = rsqrtf(ms - mu*mu + 1e-5f);
  #pragma unroll
  for (int ii = 0; ii < 32; ++ii) {
    float hn = (x[ii]-mu)*rstd*ln_g[i0+ii] + ln_b[i0+ii];
    h_lds[(i0+ii)*64 + lane] = hn;                // overwrite own rows (disjoint)
  }
  __syncthreads();                                // B5

  // k projection: wave w computes k[o] for o in [w*32, w*32+32)
  float kacc[32];
  #pragma unroll
  for (int oo = 0; oo < 32; ++oo) kacc[oo] = 0.f;
  const int o0 = w * 32;
  #pragma unroll 1
  for (int ib = 0; ib < 16; ++ib) {
    float hv[8];
    #pragma unroll
    for (int jj = 0; jj < 8; ++jj) hv[jj] = h_lds[(ib*8+jj)*64 + lane];
    #pragma unroll
    for (int oo = 0; oo < 32; ++oo) {
      const float* kpr = kp_w + (o0+oo)*Hn + ib*8;
      #pragma unroll
      for (int jj = 0; jj < 8; ++jj) kacc[oo] += hv[jj] * kpr[jj];
    }
  }
  float* k_stage = u_lds;                         // [64][132], u is dead
  float ps = 0.f;
  #pragma unroll
  for (int oo = 0; oo < 32; ++oo) {
    k_stage[lane*132 + o0 + oo] = kacc[oo];
    ps += kacc[oo]*kacc[oo];
  }
  part1[w*64+lane] = ps;
  __syncthreads();                                // B6
  if (tid < 64) {
    float nn = part1[tid] + part1[64+tid] + part1[128+tid] + part1[192+tid];
    float nrm = sqrtf(nn);
    norm_all[tile0 + tid] = nrm;
    rinv_lds[tid] = 1.0f / fmaxf(nrm, 1e-12f);
  }
  __syncthreads();                                // B7
  // coalesced write of kn = k * (1/max(||k||,eps))
  #pragma unroll
  for (int c = 0; c < 32; ++c) {
    int gi = c*256 + tid;
    int t = gi >> 7, o = gi & 127;
    kn_all[(size_t)tile0*Hn + gi] = k_stage[t*132 + o] * rinv_lds[t];
  }
}

// ---------------------------------------------------------------------------
// Phase 2: sequential gated delta-rule scan. One workgroup per batch.
// M (128x128 fp32) in VGPRs: thread = (row = tid>>1, col-half = tid&1).
// Double-buffered LDS tile prefetch (T=32 steps) removes global latency and
// the per-step load barrier; de-conflicted layout (stride 136, upper half at
// +68) removes the 2-way b128 bank conflict; 1 barrier per step.
// ---------------------------------------------------------------------------
#define T_TILE 32
#define STRIDE_ 136                // floats per step row (64 | pad4 | 64)
#define BUFSZ  (T_TILE*STRIDE_)    // 4352 floats per buffer

__global__ __launch_bounds__(256) void p2_scan(
    const float* __restrict__ kn_all, const float* __restrict__ norm_all,
    float* __restrict__ read_ws)
{
  const int tid  = threadIdx.x;
  const int lane = tid & 63;
  const int w    = tid >> 6;
  const int r    = tid >> 1;          // row 0..127
  const int ch   = tid & 1;           // column half
  const int roff = (r < 64) ? r : r + 4;
  const int b    = blockIdx.x;

  __shared__ __align__(16) float lds[2*BUFSZ];   // kn tiles, double-buffered
  __shared__ float nrmlds[2*T_TILE];
  __shared__ float red[8];                        // [parity][wave]

  float M[64];
  #pragma unroll
  for (int c = 0; c < 64; ++c) M[c] = 0.f;

  const float* knb = kn_all + (size_t)b * Ln * Hn;
  const float* nb  = norm_all + (size_t)b * Ln;

  // preload tile 0
  {
    #pragma unroll
    for (int i = 0; i < 4; ++i) {
      int gi = i*1024 + tid*4;
      float4 v = *reinterpret_cast<const float4*>(knb + gi);
      int ss = gi >> 7, col = gi & 127;
      *reinterpret_cast<float4*>(&lds[ss*STRIDE_ + ((col & 64) ? col+4 : col)]) = v;
    }
    if (tid < T_TILE) nrmlds[tid] = nb[tid];
  }
  __syncthreads();

  #pragma unroll 1
  for (int tile = 0; tile < Ln/T_TILE; ++tile) {
    const int cur = tile & 1;
    const int curbase = cur * BUFSZ;
    // issue global prefetch for next tile (latency hidden under this tile)
    float4 pf0, pf1, pf2, pf3; float pfn = 0.f;
    const bool havenext = (tile + 1) < Ln/T_TILE;
    if (havenext) {
      const float* src = knb + (size_t)(tile+1) * T_TILE * Hn;
      pf0 = *reinterpret_cast<const float4*>(src + 0*1024 + tid*4);
      pf1 = *reinterpret_cast<const float4*>(src + 1*1024 + tid*4);
      pf2 = *reinterpret_cast<const float4*>(src + 2*1024 + tid*4);
      pf3 = *reinterpret_cast<const float4*>(src + 3*1024 + tid*4);
      if (tid < T_TILE) pfn = nb[(tile+1)*T_TILE + tid];
    }

    #pragma unroll 1
    for (int s = 0; s < T_TILE; ++s) {
      const int base = curbase + s*STRIDE_;
      // kn fragment for this thread's column half (broadcast, conflict-free)
      float kn[64];
      const float* kp = &lds[base + ch*68];
      #pragma unroll
      for (int c4 = 0; c4 < 16; ++c4) {
        float4 v = *reinterpret_cast<const float4*>(kp + c4*4);
        kn[4*c4+0] = v.x; kn[4*c4+1] = v.y; kn[4*c4+2] = v.z; kn[4*c4+3] = v.w;
      }
      const float nrm = nrmlds[cur*T_TILE + s];

      float a0 = 0.f, a1 = 0.f, a2 = 0.f, a3 = 0.f;
      #pragma unroll
      for (int c = 0; c < 16; ++c) {
        a0 += M[c]    * kn[c];
        a1 += M[16+c] * kn[16+c];
        a2 += M[32+c] * kn[32+c];
        a3 += M[48+c] * kn[48+c];
      }
      float acc = (a0+a1)+(a2+a3);
      const float vp = acc + __shfl_xor(acc, 1);   // full-row M.kn

      if (tile == Ln/T_TILE - 1 && s == T_TILE - 1) {
        // last position is the query: read = M @ q, q = nrm*kn
        if (ch == 0) read_ws[b*Hn + r] = nrm * vp;
        break;
      }

      const float dr = nrm * lds[base + roff] - vp;  // d = k - vp (per row)
      float sq = (ch == 0) ? dr*dr : 0.f;
      sq += __shfl_xor(sq, 32);
      sq += __shfl_xor(sq, 16);
      sq += __shfl_xor(sq, 8);
      sq += __shfl_xor(sq, 4);
      sq += __shfl_xor(sq, 2);
      sq += __shfl_xor(sq, 1);
      const int p = s & 1;
      if (lane == 0) red[p*4 + w] = sq;

      if (s == 20 && havenext) {      // stage prefetched tile into idle buffer
        const int ob = (1-cur) * BUFSZ;
        {
          int gi = 0*1024 + tid*4; int ss = gi>>7, col = gi&127;
          *reinterpret_cast<float4*>(&lds[ob + ss*STRIDE_ + ((col&64)?col+4:col)]) = pf0;
        }
        {
          int gi = 1*1024 + tid*4; int ss = gi>>7, col = gi&127;
          *reinterpret_cast<float4*>(&lds[ob + ss*STRIDE_ + ((col&64)?col+4:col)]) = pf1;
        }
        {
          int gi = 2*1024 + tid*4; int ss = gi>>7, col = gi&127;
          *reinterpret_cast<float4*>(&lds[ob + ss*STRIDE_ + ((col&64)?col+4:col)]) = pf2;
        }
        {
          int gi = 3*1024 + tid*4; int ss = gi>>7, col = gi&127;
          *reinterpret_cast<float4*>(&lds[ob + ss*STRIDE_ + ((col&64)?col+4:col)]) = pf3;
        }
        if (tid < T_TILE) nrmlds[(1-cur)*T_TILE + tid] = pfn;
      }

      __syncthreads();                // single per-step barrier (dn2 + tile staging)
      const float dn2 = red[p*4+0] + red[p*4+1] + red[p*4+2] + red[p*4+3];

      if (sqrtf(dn2) >= 0.4f * nrm) { // fire gate (uniform across block)
        const float c1 = LAMBDA_ * dr;
        #pragma unroll
        for (int c = 0; c < 64; ++c) M[c] += c1 * kn[c];
      }
    }
  }
}

// ---------------------------------------------------------------------------
// Phase 3a: o1 = read @ rp_w^T + rp_b   (tiny)
// ---------------------------------------------------------------------------
__global__ __launch_bounds__(128) void p3a(
    const float* __restrict__ read_ws, const float* __restrict__ rp_w,
    const float* __restrict__ rp_b, float* __restrict__ o1_ws)
{
  __shared__ float rd[128];
  const int b = blockIdx.x, t = threadIdx.x;
  rd[t] = read_ws[b*Hn + t];
  __syncthreads();
  float acc = rp_b[t];
  const float* wr = rp_w + t*Hn;
  #pragma unroll 4
  for (int i = 0; i < Hn; ++i) acc += rd[i]*wr[i];
  o1_ws[b*Hn + t] = acc;
}

// ---------------------------------------------------------------------------
// Phase 3b: out = o1 @ out_w^T + out_b. Thread = one vocab column, all 64
// batches accumulated in registers; out_w streamed exactly once.
// ---------------------------------------------------------------------------
__global__ __launch_bounds__(256) void p3b(
    const float* __restrict__ o1_ws, const float* __restrict__ out_w,
    const float* __restrict__ out_b, float* __restrict__ out)
{
  __shared__ __align__(16) float o1[8192];       // [64][128]
  const int tid = threadIdx.x;
  #pragma unroll
  for (int c = 0; c < 32; ++c) o1[c*256+tid] = o1_ws[c*256+tid];
  __syncthreads();
  const int v = blockIdx.x*256 + tid;            // 125*256 == 32000 exactly
  float acc[64];
  const float ob = out_b[v];
  #pragma unroll
  for (int bb = 0; bb < 64; ++bb) acc[bb] = ob;
  const float4* wrow = reinterpret_cast<const float4*>(out_w + (size_t)v*Hn);
  #pragma unroll 1
  for (int r4 = 0; r4 < 32; ++r4) {
    const float4 wv = wrow[r4];
    #pragma unroll
    for (int bb = 0; bb < 64; ++bb) {
      const float4 ov = *reinterpret_cast<const float4*>(&o1[bb*Hn + r4*4]);
      acc[bb] += wv.x*ov.x + wv.y*ov.y + wv.z*ov.z + wv.w*ov.w;
    }
  }
  #pragma unroll
  for (int bb = 0; bb < 64; ++bb) out[(size_t)bb*Vn + v] = acc[bb];
}

// ---------------------------------------------------------------------------
extern "C" void kernel_launch(void* const* d_in, const int* in_sizes, int n_in,
                              void* d_out, int out_size, void* d_ws, size_t ws_size,
                              hipStream_t stream)
{
  const int*   seq     = (const int*)  d_in[0];
  const float* embed_w = (const float*)d_in[1];
  const float* ff_w1   = (const float*)d_in[2];
  const float* ff_b1   = (const float*)d_in[3];
  const float* ff_w2   = (const float*)d_in[4];
  const float* ff_b2   = (const float*)d_in[5];
  const float* ln_g    = (const float*)d_in[6];
  const float* ln_b    = (const float*)d_in[7];
  const float* kp_w    = (const float*)d_in[8];
  const float* rp_w    = (const float*)d_in[9];
  const float* rp_b    = (const float*)d_in[10];
  const float* out_w   = (const float*)d_in[11];
  const float* out_b   = (const float*)d_in[12];

  float* ws       = (float*)d_ws;
  float* kn_all   = ws;                               // B*L*H   = 16,777,216 f
  float* norm_all = ws + (size_t)Bn*Ln*Hn;            // B*L     = 131,072 f
  float* read_ws  = norm_all + (size_t)Bn*Ln;         // B*H     = 8,192 f
  float* o1_ws    = read_ws + Bn*Hn;                  // B*H     = 8,192 f

  p1_fused<<<dim3(2048), dim3(256), 0, stream>>>(
      seq, embed_w, ff_w1, ff_b1, ff_w2, ff_b2, ln_g, ln_b, kp_w, kn_all, norm_all);
  p2_scan<<<dim3(64), dim3(256), 0, stream>>>(kn_all, norm_all, read_ws);
  p3a<<<dim3(64), dim3(128), 0, stream>>>(read_ws, rp_w, rp_b, o1_ws);
  p3b<<<dim3(125), dim3(256), 0, stream>>>(o1_ws, out_w, out_b, (float*)d_out);
}